// Round 2
// baseline (254.856 us; speedup 1.0000x reference)
//
#include <hip/hip_runtime.h>
#include <hip/hip_bf16.h>
#include <stdint.h>

#define SEQ 4096
#define EMB 1024
#define HD  64
#define NB  4

typedef __attribute__((ext_vector_type(8))) short short8;   // 8 x bf16 (4 VGPRs)
typedef __attribute__((ext_vector_type(4))) float f32x4;

// RNE float -> bf16 bits (no NaN inputs here)
static __device__ __forceinline__ unsigned short f2bf(float f) {
    unsigned int u = __float_as_uint(f);
    u += 0x7fffu + ((u >> 16) & 1u);
    return (unsigned short)(u >> 16);
}

// ---------------------------------------------------------------------------
// Prep: Wt[m][d][e] = bf16(W_m[e][d]),  m in {q,k,v}.  3*64*1024 elements.
// ---------------------------------------------------------------------------
__global__ __launch_bounds__(256) void wprep_kernel(
        const float* __restrict__ Wq, const float* __restrict__ Wk,
        const float* __restrict__ Wv, unsigned short* __restrict__ Wt) {
    int idx = blockIdx.x * 256 + threadIdx.x;       // < 3*65536
    int m = idx >> 16;
    int r = idx & 65535;
    int d = r >> 10;
    int e = r & 1023;
    const float* W = (m == 0) ? Wq : (m == 1) ? Wk : Wv;
    Wt[idx] = f2bf(W[e * HD + d]);
}

// ---------------------------------------------------------------------------
// QKV projection. grid=256 blocks x 256 thr (4 waves). Wave owns 16 rows.
// A-frag: lane reads H[rowbase + (l&15)][kk + (l>>4)*8 + j]  (fp32 -> bf16)
// B-frag: lane reads Wt[m][(l&15)+16*nt][kk + (l>>4)*8 + j]  (contiguous 16B)
// D tile: col = lane&15 (=d), row = (lane>>4)*4 + reg (=local row)
// V is written TRANSPOSED as Vt[b][d][s'], where within each 32-key block the
// key order is permuted: phys p = 2*(s&15) + ((s>>4)&1). This makes both the
// attention P-pack (one u32 per row) and the PV B-frag reads contiguous.
// ---------------------------------------------------------------------------
__global__ __launch_bounds__(256) void qkv_kernel(
        const float* __restrict__ H, const unsigned short* __restrict__ Wt,
        unsigned short* __restrict__ Qb, unsigned short* __restrict__ Kb,
        unsigned short* __restrict__ Vt) {
    const int wid  = threadIdx.x >> 6;
    const int lane = threadIdx.x & 63;
    const int lr = lane & 15, lg = lane >> 4;
    const int rowbase = (blockIdx.x * 4 + wid) * 16;

    const float* __restrict__ a_ptr = H + (size_t)(rowbase + lr) * EMB + lg * 8;

    f32x4 acc[3][4];
    #pragma unroll
    for (int m = 0; m < 3; ++m)
        #pragma unroll
        for (int nt = 0; nt < 4; ++nt)
            acc[m][nt] = f32x4{0.f, 0.f, 0.f, 0.f};

    for (int kk = 0; kk < EMB; kk += 32) {
        f32x4 a0 = *(const f32x4*)(a_ptr + kk);
        f32x4 a1 = *(const f32x4*)(a_ptr + kk + 4);
        short8 af;
        #pragma unroll
        for (int j = 0; j < 4; ++j) {
            af[j]     = (short)f2bf(a0[j]);
            af[4 + j] = (short)f2bf(a1[j]);
        }
        #pragma unroll
        for (int m = 0; m < 3; ++m) {
            #pragma unroll
            for (int nt = 0; nt < 4; ++nt) {
                short8 bf = *(const short8*)(Wt + m * 65536 + (nt * 16 + lr) * EMB + kk + lg * 8);
                acc[m][nt] = __builtin_amdgcn_mfma_f32_16x16x32_bf16(af, bf, acc[m][nt], 0, 0, 0);
            }
        }
    }

    #pragma unroll
    for (int nt = 0; nt < 4; ++nt) {
        #pragma unroll
        for (int r = 0; r < 4; ++r) {
            int row = rowbase + lg * 4 + r;          // 0..16383
            int d   = nt * 16 + lr;
            Qb[(size_t)row * HD + d] = f2bf(acc[0][nt][r]);
            Kb[(size_t)row * HD + d] = f2bf(acc[1][nt][r]);
            int b = row >> 12;
            int s = row & (SEQ - 1);
            int p = ((s & 15) << 1) | ((s >> 4) & 1);   // sigma permutation
            int col = (s & ~31) | p;
            Vt[((size_t)b * HD + d) * SEQ + col] = f2bf(acc[2][nt][r]);
        }
    }
}

// ---------------------------------------------------------------------------
// Flash attention, causal. 1 wave per block, 16 q-rows per wave, 32 keys/iter.
// grid = 4*256 = 1024 blocks, dispatched longest-work-first.
// S-tile: col=lane&15 (=key), row=(lane>>4)*4+r (=q). Row softmax reduction is
// a 16-lane __shfl_xor butterfly (masks 1/2/4/8 stay inside the 16-group).
// P layout fix via per-wave LDS buffer, row stride 40 ushorts (80B):
//   write: u32 {p0|p1<<16} at byte row*80 + (lane&15)*4      (2-way, free)
//   read : b128 at byte (lane&15)*80 + (lane>>4)*16          (minimal aliasing)
// exp2-based softmax: t = S * log2(e)/8 is an exact base change.
// ---------------------------------------------------------------------------
__global__ __launch_bounds__(64) void attn_kernel(
        const unsigned short* __restrict__ Qb, const unsigned short* __restrict__ Kb,
        const unsigned short* __restrict__ Vt, float* __restrict__ out) {
    __shared__ unsigned short plds[16 * 40];
    const int lane = threadIdx.x;
    const int lr = lane & 15, lg = lane >> 4;
    const int bid = blockIdx.x;
    const int qt  = 255 - (bid >> 2);     // descending work
    const int b   = bid & 3;
    const int qbase = qt * 16;            // within batch

    const unsigned short* __restrict__ Qp = Qb + ((size_t)b * SEQ + qbase) * HD;
    const unsigned short* __restrict__ Kp = Kb + (size_t)b * SEQ * HD;
    const unsigned short* __restrict__ Vp = Vt + (size_t)b * HD * SEQ;

    short8 qf0 = *(const short8*)(Qp + lr * HD +      lg * 8);
    short8 qf1 = *(const short8*)(Qp + lr * HD + 32 + lg * 8);

    f32x4 o[4];
    #pragma unroll
    for (int nt = 0; nt < 4; ++nt) o[nt] = f32x4{0.f, 0.f, 0.f, 0.f};
    float mrun[4] = {-1e30f, -1e30f, -1e30f, -1e30f};
    float lrun[4] = {0.f, 0.f, 0.f, 0.f};

    const float c = 0.18033688011111793f;   // log2(e) / sqrt(64)

    const int iters = (qbase + 47) >> 5;
    for (int it = 0; it < iters; ++it) {
        const int kvb = it * 32;
        const unsigned short* kp0 = Kp + (size_t)(kvb + lr) * HD + lg * 8;
        const unsigned short* kp1 = kp0 + 16 * HD;

        f32x4 s0 = f32x4{0.f, 0.f, 0.f, 0.f};
        f32x4 s1 = f32x4{0.f, 0.f, 0.f, 0.f};
        {
            short8 k00 = *(const short8*)(kp0);
            short8 k01 = *(const short8*)(kp0 + 32);
            short8 k10 = *(const short8*)(kp1);
            short8 k11 = *(const short8*)(kp1 + 32);
            s0 = __builtin_amdgcn_mfma_f32_16x16x32_bf16(qf0, k00, s0, 0, 0, 0);
            s0 = __builtin_amdgcn_mfma_f32_16x16x32_bf16(qf1, k01, s0, 0, 0, 0);
            s1 = __builtin_amdgcn_mfma_f32_16x16x32_bf16(qf0, k10, s1, 0, 0, 0);
            s1 = __builtin_amdgcn_mfma_f32_16x16x32_bf16(qf1, k11, s1, 0, 0, 0);
        }

        const bool needmask = (kvb + 31 > qbase);
        #pragma unroll
        for (int r = 0; r < 4; ++r) {
            float v0 = s0[r] * c;
            float v1 = s1[r] * c;
            if (needmask) {
                int qg = qbase + lg * 4 + r;
                if (kvb + lr      > qg) v0 = -1e30f;
                if (kvb + 16 + lr > qg) v1 = -1e30f;
            }
            float mx = fmaxf(v0, v1);
            mx = fmaxf(mx, __shfl_xor(mx, 1));
            mx = fmaxf(mx, __shfl_xor(mx, 2));
            mx = fmaxf(mx, __shfl_xor(mx, 4));
            mx = fmaxf(mx, __shfl_xor(mx, 8));
            float mnew = fmaxf(mrun[r], mx);
            float f = exp2f(mrun[r] - mnew);
            mrun[r] = mnew;
            float p0 = exp2f(v0 - mnew);
            float p1 = exp2f(v1 - mnew);
            float rs = p0 + p1;
            rs += __shfl_xor(rs, 1);
            rs += __shfl_xor(rs, 2);
            rs += __shfl_xor(rs, 4);
            rs += __shfl_xor(rs, 8);
            lrun[r] = lrun[r] * f + rs;
            o[0][r] *= f; o[1][r] *= f; o[2][r] *= f; o[3][r] *= f;
            // pack P for keys (c, tile0)->phys 2c, (c, tile1)->phys 2c+1
            unsigned int pk = (unsigned int)f2bf(p0) | ((unsigned int)f2bf(p1) << 16);
            *(unsigned int*)&plds[(lg * 4 + r) * 40 + lr * 2] = pk;
        }

        // ensure cross-lane LDS writes land before the frag read
        asm volatile("s_waitcnt lgkmcnt(0)" ::: "memory");
        short8 pa = *(const short8*)&plds[lr * 40 + lg * 8];
        #pragma unroll
        for (int nt = 0; nt < 4; ++nt) {
            short8 vf = *(const short8*)(Vp + (size_t)(nt * 16 + lr) * SEQ + kvb + lg * 8);
            o[nt] = __builtin_amdgcn_mfma_f32_16x16x32_bf16(pa, vf, o[nt], 0, 0, 0);
        }
    }

    float* __restrict__ op = out + ((size_t)b * SEQ + qbase) * HD;
    #pragma unroll
    for (int r = 0; r < 4; ++r) {
        float inv = 1.0f / lrun[r];
        int row = lg * 4 + r;
        #pragma unroll
        for (int nt = 0; nt < 4; ++nt) {
            op[(size_t)row * HD + nt * 16 + lr] = o[nt][r] * inv;
        }
    }
}

// ---------------------------------------------------------------------------
extern "C" void kernel_launch(void* const* d_in, const int* in_sizes, int n_in,
                              void* d_out, int out_size, void* d_ws, size_t ws_size,
                              hipStream_t stream) {
    const float* H  = (const float*)d_in[0];
    const float* Wq = (const float*)d_in[1];
    const float* Wk = (const float*)d_in[2];
    const float* Wv = (const float*)d_in[3];
    float* out = (float*)d_out;

    // workspace layout (bf16): Qb[16384*64] | Kb[16384*64] | Vt[4][64][4096] | Wt[3][64][1024]
    unsigned short* Qb = (unsigned short*)d_ws;
    unsigned short* Kb = Qb + (size_t)NB * SEQ * HD;
    unsigned short* Vt = Kb + (size_t)NB * SEQ * HD;
    unsigned short* Wt = Vt + (size_t)NB * SEQ * HD;
    // total = (3*4*4096*64 + 3*64*1024) * 2 bytes ~= 6.4 MB

    wprep_kernel<<<768, 256, 0, stream>>>(Wq, Wk, Wv, Wt);
    qkv_kernel<<<(NB * SEQ) / 64, 256, 0, stream>>>(H, Wt, Qb, Kb, Vt);
    attn_kernel<<<NB * (SEQ / 16), 64, 0, stream>>>(Qb, Kb, Vt, out);
}

// Round 3
// 164.518 us; speedup vs baseline: 1.5491x; 1.5491x over previous
//
#include <hip/hip_runtime.h>
#include <hip/hip_bf16.h>
#include <stdint.h>

#define SEQ 4096
#define EMB 1024
#define HD  64
#define NB  4

typedef __attribute__((ext_vector_type(8))) short short8;   // 8 x bf16 (4 VGPRs)
typedef __attribute__((ext_vector_type(4))) float f32x4;

// RNE float -> bf16 bits (no NaN inputs here)
static __device__ __forceinline__ unsigned short f2bf(float f) {
    unsigned int u = __float_as_uint(f);
    u += 0x7fffu + ((u >> 16) & 1u);
    return (unsigned short)(u >> 16);
}

// ---------------------------------------------------------------------------
// Prep: Wt[m][d][e] = bf16(W_m[e][d]),  m in {q,k,v}.  3*64*1024 elements.
// ---------------------------------------------------------------------------
__global__ __launch_bounds__(256) void wprep_kernel(
        const float* __restrict__ Wq, const float* __restrict__ Wk,
        const float* __restrict__ Wv, unsigned short* __restrict__ Wt) {
    int idx = blockIdx.x * 256 + threadIdx.x;       // < 3*65536
    int m = idx >> 16;
    int r = idx & 65535;
    int d = r >> 10;
    int e = r & 1023;
    const float* W = (m == 0) ? Wq : (m == 1) ? Wk : Wv;
    Wt[idx] = f2bf(W[e * HD + d]);
}

// ---------------------------------------------------------------------------
// QKV projection, m-split for occupancy: block = (rowtile of 64 rows, m).
// grid = 256*3 blocks x 256 thr (4 waves) -> 3072 waves (12/CU, 3/SIMD).
// A-frag: lane reads H[rowbase + (l&15)][kk + (l>>4)*8 + j]  (fp32 -> bf16)
// B-frag: lane reads Wt[m][(l&15)+16*nt][kk + (l>>4)*8 + j]  (contiguous 16B)
// D tile: col = lane&15 (=d), row = (lane>>4)*4 + reg (=local row)
// V is written TRANSPOSED as Vt[b][d][s'], within each 32-key block keys are
// permuted: phys p = 2*(s&15) + ((s>>4)&1), matching the attention P-pack.
// ---------------------------------------------------------------------------
__global__ __launch_bounds__(256) void qkv_kernel(
        const float* __restrict__ H, const unsigned short* __restrict__ Wt,
        unsigned short* __restrict__ Qb, unsigned short* __restrict__ Kb,
        unsigned short* __restrict__ Vt) {
    const int wid  = threadIdx.x >> 6;
    const int lane = threadIdx.x & 63;
    const int lr = lane & 15, lg = lane >> 4;
    const int m  = blockIdx.x % 3;       // consecutive blocks share H rows (L2/L3)
    const int rt = blockIdx.x / 3;
    const int rowbase = (rt * 4 + wid) * 16;

    const float* __restrict__ a_ptr = H + (size_t)(rowbase + lr) * EMB + lg * 8;
    const unsigned short* __restrict__ wbase = Wt + m * 65536;

    f32x4 acc[4];
    #pragma unroll
    for (int nt = 0; nt < 4; ++nt) acc[nt] = f32x4{0.f, 0.f, 0.f, 0.f};

    for (int kk = 0; kk < EMB; kk += 32) {
        f32x4 a0 = *(const f32x4*)(a_ptr + kk);
        f32x4 a1 = *(const f32x4*)(a_ptr + kk + 4);
        short8 af;
        #pragma unroll
        for (int j = 0; j < 4; ++j) {
            af[j]     = (short)f2bf(a0[j]);
            af[4 + j] = (short)f2bf(a1[j]);
        }
        #pragma unroll
        for (int nt = 0; nt < 4; ++nt) {
            short8 bf = *(const short8*)(wbase + (nt * 16 + lr) * EMB + kk + lg * 8);
            acc[nt] = __builtin_amdgcn_mfma_f32_16x16x32_bf16(af, bf, acc[nt], 0, 0, 0);
        }
    }

    if (m == 0) {
        #pragma unroll
        for (int nt = 0; nt < 4; ++nt)
            #pragma unroll
            for (int r = 0; r < 4; ++r) {
                int row = rowbase + lg * 4 + r;
                Qb[(size_t)row * HD + nt * 16 + lr] = f2bf(acc[nt][r]);
            }
    } else if (m == 1) {
        #pragma unroll
        for (int nt = 0; nt < 4; ++nt)
            #pragma unroll
            for (int r = 0; r < 4; ++r) {
                int row = rowbase + lg * 4 + r;
                Kb[(size_t)row * HD + nt * 16 + lr] = f2bf(acc[nt][r]);
            }
    } else {
        #pragma unroll
        for (int nt = 0; nt < 4; ++nt)
            #pragma unroll
            for (int r = 0; r < 4; ++r) {
                int row = rowbase + lg * 4 + r;
                int d   = nt * 16 + lr;
                int b = row >> 12;
                int s = row & (SEQ - 1);
                int p = ((s & 15) << 1) | ((s >> 4) & 1);   // sigma permutation
                int col = (s & ~31) | p;
                Vt[((size_t)b * HD + d) * SEQ + col] = f2bf(acc[nt][r]);
            }
    }
}

// ---------------------------------------------------------------------------
// Flash attention, causal, split-K within a block.
// Block = 512 thr = 8 waves, all covering the SAME 16 q-rows; wave w handles a
// contiguous chunk of the 32-key iterations; partial (m,l,o) merged in LDS.
// grid = 4*256 = 1024 blocks (4 blocks/CU, 32 waves/CU with VGPR<=64).
// qt mapping: per-CU qt-sum equalized: i=bid>>2, p=i&63, h=i>>6,
//   qt = h*64 + (h odd ? 63-p : p)  -> each CU's 4 blocks sum to const 510.
// S-tile: col=lane&15 (=key), row=(lane>>4)*4+r (=q). Row softmax reduction is
// a 16-lane __shfl_xor butterfly. P layout fix via per-wave LDS buffer
// (aliased into this wave's merge-o region, written only after the loop):
//   write: u32 {p0|p1<<16} at byte row*80 + (lane&15)*4
//   read : b128 at byte (lane&15)*80 + (lane>>4)*16
// exp2-based softmax: t = S * log2(e)/8 is an exact base change.
// ---------------------------------------------------------------------------
__global__ __launch_bounds__(512, 8) void attn_kernel(
        const unsigned short* __restrict__ Qb, const unsigned short* __restrict__ Kb,
        const unsigned short* __restrict__ Vt, float* __restrict__ out) {
    __shared__ float lds_o[8][16][64];     // 32 KB partials; head of each wave's
                                           // 4KB slab doubles as its P buffer
    __shared__ float lds_ml[8][16][2];     // 1 KB
    const int tid  = threadIdx.x;
    const int w    = tid >> 6;
    const int lane = tid & 63;
    const int lr = lane & 15, lg = lane >> 4;

    const int bid = blockIdx.x;
    const int b   = bid & 3;
    const int i   = bid >> 2;              // 0..255
    const int p   = i & 63, h = i >> 6;
    const int qt  = (h << 6) | ((h & 1) ? (63 - p) : p);
    const int qbase = qt * 16;

    const unsigned short* __restrict__ Qp = Qb + ((size_t)b * SEQ + qbase) * HD;
    const unsigned short* __restrict__ Kp = Kb + (size_t)b * SEQ * HD;
    const unsigned short* __restrict__ Vp = Vt + (size_t)b * HD * SEQ;

    unsigned short* plds = (unsigned short*)&lds_o[w][0][0];  // 1280 B used

    short8 qf0 = *(const short8*)(Qp + lr * HD +      lg * 8);
    short8 qf1 = *(const short8*)(Qp + lr * HD + 32 + lg * 8);

    f32x4 o[4];
    #pragma unroll
    for (int nt = 0; nt < 4; ++nt) o[nt] = f32x4{0.f, 0.f, 0.f, 0.f};
    float mrun[4] = {-1e30f, -1e30f, -1e30f, -1e30f};
    float lrun[4] = {0.f, 0.f, 0.f, 0.f};

    const float c = 0.18033688011111793f;   // log2(e) / sqrt(64)

    const int total32 = (qbase + 47) >> 5;  // # of 32-key iterations
    const int niter   = (total32 + 7) >> 3;
    const int it0 = w * niter;
    const int it1 = (it0 + niter < total32) ? (it0 + niter) : total32;

    for (int it = it0; it < it1; ++it) {
        const int kvb = it * 32;
        const unsigned short* kp0 = Kp + (size_t)(kvb + lr) * HD + lg * 8;
        const unsigned short* kp1 = kp0 + 16 * HD;

        f32x4 s0 = f32x4{0.f, 0.f, 0.f, 0.f};
        f32x4 s1 = f32x4{0.f, 0.f, 0.f, 0.f};
        {
            short8 k00 = *(const short8*)(kp0);
            short8 k01 = *(const short8*)(kp0 + 32);
            short8 k10 = *(const short8*)(kp1);
            short8 k11 = *(const short8*)(kp1 + 32);
            s0 = __builtin_amdgcn_mfma_f32_16x16x32_bf16(qf0, k00, s0, 0, 0, 0);
            s0 = __builtin_amdgcn_mfma_f32_16x16x32_bf16(qf1, k01, s0, 0, 0, 0);
            s1 = __builtin_amdgcn_mfma_f32_16x16x32_bf16(qf0, k10, s1, 0, 0, 0);
            s1 = __builtin_amdgcn_mfma_f32_16x16x32_bf16(qf1, k11, s1, 0, 0, 0);
        }

        const bool needmask = (kvb + 31 > qbase);
        #pragma unroll
        for (int r = 0; r < 4; ++r) {
            float v0 = s0[r] * c;
            float v1 = s1[r] * c;
            if (needmask) {
                int qg = qbase + lg * 4 + r;
                if (kvb + lr      > qg) v0 = -1e30f;
                if (kvb + 16 + lr > qg) v1 = -1e30f;
            }
            float mx = fmaxf(v0, v1);
            mx = fmaxf(mx, __shfl_xor(mx, 1));
            mx = fmaxf(mx, __shfl_xor(mx, 2));
            mx = fmaxf(mx, __shfl_xor(mx, 4));
            mx = fmaxf(mx, __shfl_xor(mx, 8));
            float mnew = fmaxf(mrun[r], mx);
            float f = exp2f(mrun[r] - mnew);
            mrun[r] = mnew;
            float p0 = exp2f(v0 - mnew);
            float p1 = exp2f(v1 - mnew);
            float rs = p0 + p1;
            rs += __shfl_xor(rs, 1);
            rs += __shfl_xor(rs, 2);
            rs += __shfl_xor(rs, 4);
            rs += __shfl_xor(rs, 8);
            lrun[r] = lrun[r] * f + rs;
            o[0][r] *= f; o[1][r] *= f; o[2][r] *= f; o[3][r] *= f;
            // pack P for keys (c, tile0)->phys 2c, (c, tile1)->phys 2c+1
            unsigned int pk = (unsigned int)f2bf(p0) | ((unsigned int)f2bf(p1) << 16);
            *(unsigned int*)&plds[(lg * 4 + r) * 40 + lr * 2] = pk;
        }

        // ensure cross-lane LDS writes land before the frag read
        asm volatile("s_waitcnt lgkmcnt(0)" ::: "memory");
        short8 pa = *(const short8*)&plds[lr * 40 + lg * 8];
        #pragma unroll
        for (int nt = 0; nt < 4; ++nt) {
            short8 vf = *(const short8*)(Vp + (size_t)(nt * 16 + lr) * SEQ + kvb + lg * 8);
            o[nt] = __builtin_amdgcn_mfma_f32_16x16x32_bf16(pa, vf, o[nt], 0, 0, 0);
        }
    }

    // ---- write partials (overwrites this wave's P buffer region — loop done)
    #pragma unroll
    for (int nt = 0; nt < 4; ++nt)
        #pragma unroll
        for (int r = 0; r < 4; ++r)
            lds_o[w][lg * 4 + r][nt * 16 + lr] = o[nt][r];
    if (lr == 0) {
        #pragma unroll
        for (int r = 0; r < 4; ++r) {
            lds_ml[w][lg * 4 + r][0] = mrun[r];
            lds_ml[w][lg * 4 + r][1] = lrun[r];
        }
    }
    __syncthreads();

    // ---- merge 8 partials: 512 threads over 16 rows x 32 col-pairs
    const int row = tid >> 5;
    const int c2  = (tid & 31) * 2;
    float M = -1e30f;
    #pragma unroll
    for (int ww = 0; ww < 8; ++ww) M = fmaxf(M, lds_ml[ww][row][0]);
    float L = 0.f, a0 = 0.f, a1 = 0.f;
    #pragma unroll
    for (int ww = 0; ww < 8; ++ww) {
        float wt = exp2f(lds_ml[ww][row][0] - M);
        L  += wt * lds_ml[ww][row][1];
        a0 += wt * lds_o[ww][row][c2];
        a1 += wt * lds_o[ww][row][c2 + 1];
    }
    float invL = 1.0f / L;
    float2 res;
    res.x = a0 * invL;
    res.y = a1 * invL;
    *(float2*)(out + ((size_t)b * SEQ + qbase + row) * HD + c2) = res;
}

// ---------------------------------------------------------------------------
extern "C" void kernel_launch(void* const* d_in, const int* in_sizes, int n_in,
                              void* d_out, int out_size, void* d_ws, size_t ws_size,
                              hipStream_t stream) {
    const float* H  = (const float*)d_in[0];
    const float* Wq = (const float*)d_in[1];
    const float* Wk = (const float*)d_in[2];
    const float* Wv = (const float*)d_in[3];
    float* out = (float*)d_out;

    // workspace layout (bf16): Qb[16384*64] | Kb[16384*64] | Vt[4][64][4096] | Wt[3][64][1024]
    unsigned short* Qb = (unsigned short*)d_ws;
    unsigned short* Kb = Qb + (size_t)NB * SEQ * HD;
    unsigned short* Vt = Kb + (size_t)NB * SEQ * HD;
    unsigned short* Wt = Vt + (size_t)NB * SEQ * HD;
    // total = (3*4*4096*64 + 3*64*1024) * 2 bytes ~= 6.4 MB

    wprep_kernel<<<768, 256, 0, stream>>>(Wq, Wk, Wv, Wt);
    qkv_kernel<<<256 * 3, 256, 0, stream>>>(H, Wt, Qb, Kb, Vt);
    attn_kernel<<<NB * (SEQ / 16), 512, 0, stream>>>(Qb, Kb, Vt, out);
}

// Round 5
// 138.675 us; speedup vs baseline: 1.8378x; 1.1864x over previous
//
#include <hip/hip_runtime.h>
#include <hip/hip_bf16.h>
#include <stdint.h>

#define SEQ 4096
#define EMB 1024
#define HD  64
#define NB  4

typedef __attribute__((ext_vector_type(8))) short short8;   // 8 x bf16 (4 VGPRs)
typedef __attribute__((ext_vector_type(4))) float f32x4;

// RNE float -> bf16 bits (no NaN inputs here)
static __device__ __forceinline__ unsigned short f2bf(float f) {
    unsigned int u = __float_as_uint(f);
    u += 0x7fffu + ((u >> 16) & 1u);
    return (unsigned short)(u >> 16);
}

// ---------------------------------------------------------------------------
// Prep: Wt[m][d][e] = bf16(W_m[e][d]),  m in {q,k,v}.  3*64*1024 elements.
// ---------------------------------------------------------------------------
__global__ __launch_bounds__(256) void wprep_kernel(
        const float* __restrict__ Wq, const float* __restrict__ Wk,
        const float* __restrict__ Wv, unsigned short* __restrict__ Wt) {
    int idx = blockIdx.x * 256 + threadIdx.x;       // < 3*65536
    int m = idx >> 16;
    int r = idx & 65535;
    int d = r >> 10;
    int e = r & 1023;
    const float* W = (m == 0) ? Wq : (m == 1) ? Wk : Wv;
    Wt[idx] = f2bf(W[e * HD + d]);
}

// ---------------------------------------------------------------------------
// QKV projection, m-split for occupancy: block = (rowtile of 64 rows, m).
// grid = 256*3 blocks x 256 thr (4 waves) -> 3072 waves (12/CU, 3/SIMD).
// V is written TRANSPOSED as Vt[b][d][s'] with per-32-block key permutation
//   sigma(t) = ((t&12)<<1) | (t&3) | ((t&16)>>2)
// matching the attention kernel's in-register P fragment layout (swapped QK^T:
// lane holds P[key = lg*4+r (tile0) / 16+lg*4+r (tile1)][q=lr], packed at
// B-frag position k = lg*8 + r (+4 for tile1)).
// ---------------------------------------------------------------------------
__global__ __launch_bounds__(256) void qkv_kernel(
        const float* __restrict__ H, const unsigned short* __restrict__ Wt,
        unsigned short* __restrict__ Qb, unsigned short* __restrict__ Kb,
        unsigned short* __restrict__ Vt) {
    const int wid  = threadIdx.x >> 6;
    const int lane = threadIdx.x & 63;
    const int lr = lane & 15, lg = lane >> 4;
    const int m  = blockIdx.x % 3;       // consecutive blocks share H rows (L2/L3)
    const int rt = blockIdx.x / 3;
    const int rowbase = (rt * 4 + wid) * 16;

    const float* __restrict__ a_ptr = H + (size_t)(rowbase + lr) * EMB + lg * 8;
    const unsigned short* __restrict__ wbase = Wt + m * 65536;

    f32x4 acc[4];
    #pragma unroll
    for (int nt = 0; nt < 4; ++nt) acc[nt] = f32x4{0.f, 0.f, 0.f, 0.f};

    for (int kk = 0; kk < EMB; kk += 32) {
        f32x4 a0 = *(const f32x4*)(a_ptr + kk);
        f32x4 a1 = *(const f32x4*)(a_ptr + kk + 4);
        short8 af;
        #pragma unroll
        for (int j = 0; j < 4; ++j) {
            af[j]     = (short)f2bf(a0[j]);
            af[4 + j] = (short)f2bf(a1[j]);
        }
        #pragma unroll
        for (int nt = 0; nt < 4; ++nt) {
            short8 bf = *(const short8*)(wbase + (nt * 16 + lr) * EMB + kk + lg * 8);
            acc[nt] = __builtin_amdgcn_mfma_f32_16x16x32_bf16(af, bf, acc[nt], 0, 0, 0);
        }
    }

    if (m == 0) {
        #pragma unroll
        for (int nt = 0; nt < 4; ++nt)
            #pragma unroll
            for (int r = 0; r < 4; ++r) {
                int row = rowbase + lg * 4 + r;
                Qb[(size_t)row * HD + nt * 16 + lr] = f2bf(acc[nt][r]);
            }
    } else if (m == 1) {
        #pragma unroll
        for (int nt = 0; nt < 4; ++nt)
            #pragma unroll
            for (int r = 0; r < 4; ++r) {
                int row = rowbase + lg * 4 + r;
                Kb[(size_t)row * HD + nt * 16 + lr] = f2bf(acc[nt][r]);
            }
    } else {
        #pragma unroll
        for (int nt = 0; nt < 4; ++nt)
            #pragma unroll
            for (int r = 0; r < 4; ++r) {
                int row = rowbase + lg * 4 + r;
                int d   = nt * 16 + lr;
                int b = row >> 12;
                int s = row & (SEQ - 1);
                int t = s & 31;
                int pp = ((t & 12) << 1) | (t & 3) | ((t & 16) >> 2);  // sigma
                int col = (s & ~31) | pp;
                Vt[((size_t)b * HD + d) * SEQ + col] = f2bf(acc[nt][r]);
            }
    }
}

// ---------------------------------------------------------------------------
// Flash attention, causal, split-K within a block, SWAPPED QK^T.
// Block = 512 thr = 8 waves over the SAME 16 q-rows; wave w handles
// iterations it = w, w+8, ... (interleaved, balanced +-1, lockstep L2).
// S^T = mfma(K_frag, Q_frag): D col = q (lane&15), row = key (lg*4+r).
// Per-lane softmax for q=lr: in-register max/sum over 8 keys + 2 shuffles
// (xor 16/32) for the cross-lg max. lrun is per-lane, reduced at epilogue.
// P stays in registers: packed into PV B-frag pb (k = lg*8 + r / +4).
// PV: o[nt] = mfma(Vt_frag, pb, o[nt]) -> O[q=lr][d = nt*16+lg*4+r].
// Defer-max (THR=8 in exp2 domain): skip o-rescale while max growth <= 8.
// Partial (m,l,o) merged across waves via LDS (o padded stride 65).
// exp2-based softmax: t = S * log2(e)/8 is an exact base change.
// ---------------------------------------------------------------------------
__global__ __launch_bounds__(512, 8) void attn_kernel(
        const unsigned short* __restrict__ Qb, const unsigned short* __restrict__ Kb,
        const unsigned short* __restrict__ Vt, float* __restrict__ out) {
    __shared__ float lds_o[8][16][65];     // 33.3 KB partials (padded)
    __shared__ float lds_ml[8][16][2];     // 1 KB
    const int tid  = threadIdx.x;
    const int w    = tid >> 6;
    const int lane = tid & 63;
    const int lr = lane & 15, lg = lane >> 4;

    const int bid = blockIdx.x;
    const int b   = bid & 3;
    const int i   = bid >> 2;              // 0..255
    const int p   = i & 63, h = i >> 6;
    const int qt  = (h << 6) | ((h & 1) ? (63 - p) : p);   // per-CU balance
    const int qbase = qt * 16;

    const unsigned short* __restrict__ Qp = Qb + ((size_t)b * SEQ + qbase) * HD;
    const unsigned short* __restrict__ Kp = Kb + (size_t)b * SEQ * HD;
    const unsigned short* __restrict__ Vp = Vt + (size_t)b * HD * SEQ;

    short8 qf0 = *(const short8*)(Qp + lr * HD +      lg * 8);
    short8 qf1 = *(const short8*)(Qp + lr * HD + 32 + lg * 8);

    f32x4 o[4];
    #pragma unroll
    for (int nt = 0; nt < 4; ++nt) o[nt] = f32x4{0.f, 0.f, 0.f, 0.f};
    float mrun = -1e30f;
    float lrun = 0.f;

    const float c = 0.18033688011111793f;   // log2(e) / sqrt(64)
    const int total32 = (qbase + 47) >> 5;  // # of 32-key iterations

    for (int it = w; it < total32; it += 8) {
        const int kvb = it * 32;
        const unsigned short* kp0 = Kp + (size_t)(kvb + lr) * HD + lg * 8;
        const unsigned short* kp1 = kp0 + 16 * HD;

        f32x4 s0 = f32x4{0.f, 0.f, 0.f, 0.f};
        f32x4 s1 = f32x4{0.f, 0.f, 0.f, 0.f};
        {
            short8 k00 = *(const short8*)(kp0);
            short8 k01 = *(const short8*)(kp0 + 32);
            short8 k10 = *(const short8*)(kp1);
            short8 k11 = *(const short8*)(kp1 + 32);
            // swapped: A = K rows (keys), B = Q rows (q) -> S^T
            s0 = __builtin_amdgcn_mfma_f32_16x16x32_bf16(k00, qf0, s0, 0, 0, 0);
            s0 = __builtin_amdgcn_mfma_f32_16x16x32_bf16(k01, qf1, s0, 0, 0, 0);
            s1 = __builtin_amdgcn_mfma_f32_16x16x32_bf16(k10, qf0, s1, 0, 0, 0);
            s1 = __builtin_amdgcn_mfma_f32_16x16x32_bf16(k11, qf1, s1, 0, 0, 0);
        }

        float v0[4], v1[4];
        #pragma unroll
        for (int r = 0; r < 4; ++r) { v0[r] = s0[r] * c; v1[r] = s1[r] * c; }
        if (kvb + 31 > qbase) {            // diagonal tile: causal mask
            const int qg = qbase + lr;
            #pragma unroll
            for (int r = 0; r < 4; ++r) {
                if (kvb + lg * 4 + r      > qg) v0[r] = -1e30f;
                if (kvb + 16 + lg * 4 + r > qg) v1[r] = -1e30f;
            }
        }

        // per-lane max over this lane's 8 keys, then cross-lg (same q) reduce
        float mx = fmaxf(fmaxf(fmaxf(v0[0], v0[1]), fmaxf(v0[2], v0[3])),
                         fmaxf(fmaxf(v1[0], v1[1]), fmaxf(v1[2], v1[3])));
        mx = fmaxf(mx, __shfl_xor(mx, 16));
        mx = fmaxf(mx, __shfl_xor(mx, 32));

        // defer-max: only rescale when max grew by more than THR=8
        if (!__all(mx <= mrun + 8.f)) {
            float mnew = fmaxf(mrun, mx);
            float f = exp2f(mrun - mnew);
            mrun = mnew;
            lrun *= f;
            #pragma unroll
            for (int nt = 0; nt < 4; ++nt) o[nt] *= f;
        }

        short8 pb;
        float rs = 0.f;
        #pragma unroll
        for (int r = 0; r < 4; ++r) {
            float p0 = exp2f(v0[r] - mrun);
            float p1 = exp2f(v1[r] - mrun);
            rs += p0 + p1;
            pb[r]     = (short)f2bf(p0);
            pb[4 + r] = (short)f2bf(p1);
        }
        lrun += rs;

        #pragma unroll
        for (int nt = 0; nt < 4; ++nt) {
            short8 vf = *(const short8*)(Vp + (size_t)(nt * 16 + lr) * SEQ + kvb + lg * 8);
            o[nt] = __builtin_amdgcn_mfma_f32_16x16x32_bf16(vf, pb, o[nt], 0, 0, 0);
        }
    }

    // per-lane lrun -> per-q total (sum across lg groups)
    lrun += __shfl_xor(lrun, 16);
    lrun += __shfl_xor(lrun, 32);

    // ---- write partials: o[nt][r] = O[q=lr][d = nt*16+lg*4+r]
    #pragma unroll
    for (int nt = 0; nt < 4; ++nt)
        #pragma unroll
        for (int r = 0; r < 4; ++r)
            lds_o[w][lr][nt * 16 + lg * 4 + r] = o[nt][r];
    if (lane < 16) {
        lds_ml[w][lane][0] = mrun;
        lds_ml[w][lane][1] = lrun;
    }
    __syncthreads();

    // ---- merge 8 partials: 512 threads over 16 rows x 32 col-pairs
    const int row = tid >> 5;
    const int c2  = (tid & 31) * 2;
    float M = -1e30f;
    #pragma unroll
    for (int ww = 0; ww < 8; ++ww) M = fmaxf(M, lds_ml[ww][row][0]);
    float L = 0.f, a0 = 0.f, a1 = 0.f;
    #pragma unroll
    for (int ww = 0; ww < 8; ++ww) {
        float wt = exp2f(lds_ml[ww][row][0] - M);
        L  += wt * lds_ml[ww][row][1];
        a0 += wt * lds_o[ww][row][c2];
        a1 += wt * lds_o[ww][row][c2 + 1];
    }
    float invL = 1.0f / L;
    float2 res;
    res.x = a0 * invL;
    res.y = a1 * invL;
    *(float2*)(out + ((size_t)b * SEQ + qbase + row) * HD + c2) = res;
}

// ---------------------------------------------------------------------------
extern "C" void kernel_launch(void* const* d_in, const int* in_sizes, int n_in,
                              void* d_out, int out_size, void* d_ws, size_t ws_size,
                              hipStream_t stream) {
    const float* H  = (const float*)d_in[0];
    const float* Wq = (const float*)d_in[1];
    const float* Wk = (const float*)d_in[2];
    const float* Wv = (const float*)d_in[3];
    float* out = (float*)d_out;

    // workspace layout (bf16): Qb[16384*64] | Kb[16384*64] | Vt[4][64][4096] | Wt[3][64][1024]
    unsigned short* Qb = (unsigned short*)d_ws;
    unsigned short* Kb = Qb + (size_t)NB * SEQ * HD;
    unsigned short* Vt = Kb + (size_t)NB * SEQ * HD;
    unsigned short* Wt = Vt + (size_t)NB * SEQ * HD;
    // total = (3*4*4096*64 + 3*64*1024) * 2 bytes ~= 6.4 MB

    wprep_kernel<<<768, 256, 0, stream>>>(Wq, Wk, Wv, Wt);
    qkv_kernel<<<256 * 3, 256, 0, stream>>>(H, Wt, Qb, Kb, Vt);
    attn_kernel<<<NB * (SEQ / 16), 512, 0, stream>>>(Qb, Kb, Vt, out);
}

// Round 6
// 127.882 us; speedup vs baseline: 1.9929x; 1.0844x over previous
//
#include <hip/hip_runtime.h>
#include <hip/hip_bf16.h>
#include <stdint.h>

#define SEQ 4096
#define EMB 1024
#define HD  64
#define NB  4

typedef __attribute__((ext_vector_type(8))) short short8;   // 8 x bf16 (4 VGPRs)
typedef __attribute__((ext_vector_type(4))) float f32x4;

// RNE float -> bf16 bits (no NaN inputs here)
static __device__ __forceinline__ unsigned short f2bf(float f) {
    unsigned int u = __float_as_uint(f);
    u += 0x7fffu + ((u >> 16) & 1u);
    return (unsigned short)(u >> 16);
}

// ---------------------------------------------------------------------------
// Prep: Wt[m][d][e] = bf16(W_m[e][d]),  m in {q,k,v}.  3*64*1024 elements.
// ---------------------------------------------------------------------------
__global__ __launch_bounds__(256) void wprep_kernel(
        const float* __restrict__ Wq, const float* __restrict__ Wk,
        const float* __restrict__ Wv, unsigned short* __restrict__ Wt) {
    int idx = blockIdx.x * 256 + threadIdx.x;       // < 3*65536
    int m = idx >> 16;
    int r = idx & 65535;
    int d = r >> 10;
    int e = r & 1023;
    const float* W = (m == 0) ? Wq : (m == 1) ? Wk : Wv;
    Wt[idx] = f2bf(W[e * HD + d]);
}

// ---------------------------------------------------------------------------
// QKV projection, fused-m + intra-block K-split.
// Block = 16 rows x 256 thr (4 waves); wave w covers K in [w*256, w*256+256).
// H is read ONCE (64 MB total); one A-frag convert feeds 12 MFMAs (3m x 4nt).
// grid = 1024 blocks -> 4096 waves (16/CU with VGPR<=128, LDS 24KB).
// Cross-wave reduce: pairwise via LDS (w2,w3 -> slab; w0,w1 add; w1 -> slab;
// w0 adds and writes the epilogue).
// D tile: col = lane&15 (=d within nt), row = (lane>>4)*4 + reg (=local row).
// V is written TRANSPOSED as Vt[b][d][s'] with per-32-block key permutation
//   sigma(t) = ((t&12)<<1) | (t&3) | ((t&16)>>2)
// matching the attention kernel's in-register P fragment layout.
// ---------------------------------------------------------------------------
__global__ __launch_bounds__(256, 4) void qkv_kernel(
        const float* __restrict__ H, const unsigned short* __restrict__ Wt,
        unsigned short* __restrict__ Qb, unsigned short* __restrict__ Kb,
        unsigned short* __restrict__ Vt) {
    __shared__ float lds_red[2][16][192];   // 24 KB, two reduction slabs
    const int wid  = threadIdx.x >> 6;
    const int lane = threadIdx.x & 63;
    const int lr = lane & 15, lg = lane >> 4;
    const int rowbase = blockIdx.x * 16;

    const float* __restrict__ a_ptr =
        H + (size_t)(rowbase + lr) * EMB + wid * 256 + lg * 8;
    const unsigned short* __restrict__ wb = Wt + wid * 256 + lg * 8;

    f32x4 acc[3][4];
    #pragma unroll
    for (int m = 0; m < 3; ++m)
        #pragma unroll
        for (int nt = 0; nt < 4; ++nt)
            acc[m][nt] = f32x4{0.f, 0.f, 0.f, 0.f};

    for (int kk = 0; kk < 256; kk += 32) {
        f32x4 a0 = *(const f32x4*)(a_ptr + kk);
        f32x4 a1 = *(const f32x4*)(a_ptr + kk + 4);
        short8 af;
        #pragma unroll
        for (int j = 0; j < 4; ++j) {
            af[j]     = (short)f2bf(a0[j]);
            af[4 + j] = (short)f2bf(a1[j]);
        }
        #pragma unroll
        for (int m = 0; m < 3; ++m) {
            #pragma unroll
            for (int nt = 0; nt < 4; ++nt) {
                short8 bf = *(const short8*)(wb + m * 65536 + (nt * 16 + lr) * EMB + kk);
                acc[m][nt] = __builtin_amdgcn_mfma_f32_16x16x32_bf16(af, bf, acc[m][nt], 0, 0, 0);
            }
        }
    }

    // ---- pairwise cross-wave reduction (all barriers block-uniform)
    if (wid >= 2) {
        #pragma unroll
        for (int m = 0; m < 3; ++m)
            #pragma unroll
            for (int nt = 0; nt < 4; ++nt)
                #pragma unroll
                for (int r = 0; r < 4; ++r)
                    lds_red[wid - 2][lg * 4 + r][m * 64 + nt * 16 + lr] = acc[m][nt][r];
    }
    __syncthreads();
    if (wid < 2) {
        #pragma unroll
        for (int m = 0; m < 3; ++m)
            #pragma unroll
            for (int nt = 0; nt < 4; ++nt)
                #pragma unroll
                for (int r = 0; r < 4; ++r)
                    acc[m][nt][r] += lds_red[wid][lg * 4 + r][m * 64 + nt * 16 + lr];
    }
    __syncthreads();
    if (wid == 1) {
        #pragma unroll
        for (int m = 0; m < 3; ++m)
            #pragma unroll
            for (int nt = 0; nt < 4; ++nt)
                #pragma unroll
                for (int r = 0; r < 4; ++r)
                    lds_red[0][lg * 4 + r][m * 64 + nt * 16 + lr] = acc[m][nt][r];
    }
    __syncthreads();
    if (wid == 0) {
        #pragma unroll
        for (int m = 0; m < 3; ++m)
            #pragma unroll
            for (int nt = 0; nt < 4; ++nt)
                #pragma unroll
                for (int r = 0; r < 4; ++r)
                    acc[m][nt][r] += lds_red[0][lg * 4 + r][m * 64 + nt * 16 + lr];

        #pragma unroll
        for (int nt = 0; nt < 4; ++nt)
            #pragma unroll
            for (int r = 0; r < 4; ++r) {
                int row = rowbase + lg * 4 + r;
                int d   = nt * 16 + lr;
                Qb[(size_t)row * HD + d] = f2bf(acc[0][nt][r]);
                Kb[(size_t)row * HD + d] = f2bf(acc[1][nt][r]);
                int b = row >> 12;
                int s = row & (SEQ - 1);
                int t = s & 31;
                int pp = ((t & 12) << 1) | (t & 3) | ((t & 16) >> 2);  // sigma
                int col = (s & ~31) | pp;
                Vt[((size_t)b * HD + d) * SEQ + col] = f2bf(acc[2][nt][r]);
            }
    }
}

// ---------------------------------------------------------------------------
// Flash attention, causal, split-K within a block, SWAPPED QK^T.
// Block = 512 thr = 8 waves over the SAME 16 q-rows; wave w handles
// iterations it = w, w+8, ... (interleaved, balanced +-1, lockstep L2).
// S^T = mfma(K_frag, Q_frag): D col = q (lane&15), row = key (lg*4+r).
// Per-lane softmax for q=lr: in-register max/sum over 8 keys + 2 shuffles
// (xor 16/32) for the cross-lg max. lrun is per-lane, reduced at epilogue.
// P stays in registers: packed into PV B-frag pb (k = lg*8 + r / +4).
// PV: o[nt] = mfma(Vt_frag, pb, o[nt]) -> O[q=lr][d = nt*16+lg*4+r].
// Defer-max (THR=8 in exp2 domain): skip o-rescale while max growth <= 8.
// Partial (m,l,o) merged across waves via LDS (o padded stride 65).
// exp2-based softmax: t = S * log2(e)/8 is an exact base change.
// ---------------------------------------------------------------------------
__global__ __launch_bounds__(512, 8) void attn_kernel(
        const unsigned short* __restrict__ Qb, const unsigned short* __restrict__ Kb,
        const unsigned short* __restrict__ Vt, float* __restrict__ out) {
    __shared__ float lds_o[8][16][65];     // 33.3 KB partials (padded)
    __shared__ float lds_ml[8][16][2];     // 1 KB
    const int tid  = threadIdx.x;
    const int w    = tid >> 6;
    const int lane = tid & 63;
    const int lr = lane & 15, lg = lane >> 4;

    const int bid = blockIdx.x;
    const int b   = bid & 3;
    const int i   = bid >> 2;              // 0..255
    const int p   = i & 63, h = i >> 6;
    const int qt  = (h << 6) | ((h & 1) ? (63 - p) : p);   // per-CU balance
    const int qbase = qt * 16;

    const unsigned short* __restrict__ Qp = Qb + ((size_t)b * SEQ + qbase) * HD;
    const unsigned short* __restrict__ Kp = Kb + (size_t)b * SEQ * HD;
    const unsigned short* __restrict__ Vp = Vt + (size_t)b * HD * SEQ;

    short8 qf0 = *(const short8*)(Qp + lr * HD +      lg * 8);
    short8 qf1 = *(const short8*)(Qp + lr * HD + 32 + lg * 8);

    f32x4 o[4];
    #pragma unroll
    for (int nt = 0; nt < 4; ++nt) o[nt] = f32x4{0.f, 0.f, 0.f, 0.f};
    float mrun = -1e30f;
    float lrun = 0.f;

    const float c = 0.18033688011111793f;   // log2(e) / sqrt(64)
    const int total32 = (qbase + 47) >> 5;  // # of 32-key iterations

    for (int it = w; it < total32; it += 8) {
        const int kvb = it * 32;
        const unsigned short* kp0 = Kp + (size_t)(kvb + lr) * HD + lg * 8;
        const unsigned short* kp1 = kp0 + 16 * HD;

        f32x4 s0 = f32x4{0.f, 0.f, 0.f, 0.f};
        f32x4 s1 = f32x4{0.f, 0.f, 0.f, 0.f};
        {
            short8 k00 = *(const short8*)(kp0);
            short8 k01 = *(const short8*)(kp0 + 32);
            short8 k10 = *(const short8*)(kp1);
            short8 k11 = *(const short8*)(kp1 + 32);
            // swapped: A = K rows (keys), B = Q rows (q) -> S^T
            s0 = __builtin_amdgcn_mfma_f32_16x16x32_bf16(k00, qf0, s0, 0, 0, 0);
            s0 = __builtin_amdgcn_mfma_f32_16x16x32_bf16(k01, qf1, s0, 0, 0, 0);
            s1 = __builtin_amdgcn_mfma_f32_16x16x32_bf16(k10, qf0, s1, 0, 0, 0);
            s1 = __builtin_amdgcn_mfma_f32_16x16x32_bf16(k11, qf1, s1, 0, 0, 0);
        }

        float v0[4], v1[4];
        #pragma unroll
        for (int r = 0; r < 4; ++r) { v0[r] = s0[r] * c; v1[r] = s1[r] * c; }
        if (kvb + 31 > qbase) {            // diagonal tile: causal mask
            const int qg = qbase + lr;
            #pragma unroll
            for (int r = 0; r < 4; ++r) {
                if (kvb + lg * 4 + r      > qg) v0[r] = -1e30f;
                if (kvb + 16 + lg * 4 + r > qg) v1[r] = -1e30f;
            }
        }

        // per-lane max over this lane's 8 keys, then cross-lg (same q) reduce
        float mx = fmaxf(fmaxf(fmaxf(v0[0], v0[1]), fmaxf(v0[2], v0[3])),
                         fmaxf(fmaxf(v1[0], v1[1]), fmaxf(v1[2], v1[3])));
        mx = fmaxf(mx, __shfl_xor(mx, 16));
        mx = fmaxf(mx, __shfl_xor(mx, 32));

        // defer-max: only rescale when max grew by more than THR=8
        if (!__all(mx <= mrun + 8.f)) {
            float mnew = fmaxf(mrun, mx);
            float f = exp2f(mrun - mnew);
            mrun = mnew;
            lrun *= f;
            #pragma unroll
            for (int nt = 0; nt < 4; ++nt) o[nt] *= f;
        }

        short8 pb;
        float rs = 0.f;
        #pragma unroll
        for (int r = 0; r < 4; ++r) {
            float p0 = exp2f(v0[r] - mrun);
            float p1 = exp2f(v1[r] - mrun);
            rs += p0 + p1;
            pb[r]     = (short)f2bf(p0);
            pb[4 + r] = (short)f2bf(p1);
        }
        lrun += rs;

        #pragma unroll
        for (int nt = 0; nt < 4; ++nt) {
            short8 vf = *(const short8*)(Vp + (size_t)(nt * 16 + lr) * SEQ + kvb + lg * 8);
            o[nt] = __builtin_amdgcn_mfma_f32_16x16x32_bf16(vf, pb, o[nt], 0, 0, 0);
        }
    }

    // per-lane lrun -> per-q total (sum across lg groups)
    lrun += __shfl_xor(lrun, 16);
    lrun += __shfl_xor(lrun, 32);

    // ---- write partials: o[nt][r] = O[q=lr][d = nt*16+lg*4+r]
    #pragma unroll
    for (int nt = 0; nt < 4; ++nt)
        #pragma unroll
        for (int r = 0; r < 4; ++r)
            lds_o[w][lr][nt * 16 + lg * 4 + r] = o[nt][r];
    if (lane < 16) {
        lds_ml[w][lane][0] = mrun;
        lds_ml[w][lane][1] = lrun;
    }
    __syncthreads();

    // ---- merge 8 partials: 512 threads over 16 rows x 32 col-pairs
    const int row = tid >> 5;
    const int c2  = (tid & 31) * 2;
    float M = -1e30f;
    #pragma unroll
    for (int ww = 0; ww < 8; ++ww) M = fmaxf(M, lds_ml[ww][row][0]);
    float L = 0.f, a0 = 0.f, a1 = 0.f;
    #pragma unroll
    for (int ww = 0; ww < 8; ++ww) {
        float wt = exp2f(lds_ml[ww][row][0] - M);
        L  += wt * lds_ml[ww][row][1];
        a0 += wt * lds_o[ww][row][c2];
        a1 += wt * lds_o[ww][row][c2 + 1];
    }
    float invL = 1.0f / L;
    float2 res;
    res.x = a0 * invL;
    res.y = a1 * invL;
    *(float2*)(out + ((size_t)b * SEQ + qbase + row) * HD + c2) = res;
}

// ---------------------------------------------------------------------------
extern "C" void kernel_launch(void* const* d_in, const int* in_sizes, int n_in,
                              void* d_out, int out_size, void* d_ws, size_t ws_size,
                              hipStream_t stream) {
    const float* H  = (const float*)d_in[0];
    const float* Wq = (const float*)d_in[1];
    const float* Wk = (const float*)d_in[2];
    const float* Wv = (const float*)d_in[3];
    float* out = (float*)d_out;

    // workspace layout (bf16): Qb[16384*64] | Kb[16384*64] | Vt[4][64][4096] | Wt[3][64][1024]
    unsigned short* Qb = (unsigned short*)d_ws;
    unsigned short* Kb = Qb + (size_t)NB * SEQ * HD;
    unsigned short* Vt = Kb + (size_t)NB * SEQ * HD;
    unsigned short* Wt = Vt + (size_t)NB * SEQ * HD;
    // total = (3*4*4096*64 + 3*64*1024) * 2 bytes ~= 6.4 MB

    wprep_kernel<<<768, 256, 0, stream>>>(Wq, Wk, Wv, Wt);
    qkv_kernel<<<NB * SEQ / 16, 256, 0, stream>>>(H, Wt, Qb, Kb, Vt);
    attn_kernel<<<NB * (SEQ / 16), 512, 0, stream>>>(Qb, Kb, Vt, out);
}

// Round 7
// 112.655 us; speedup vs baseline: 2.2623x; 1.1352x over previous
//
#include <hip/hip_runtime.h>
#include <hip/hip_bf16.h>
#include <stdint.h>

#define SEQ 4096
#define EMB 1024
#define HD  64
#define NB  4

typedef __attribute__((ext_vector_type(8))) short short8;   // 8 x bf16 (4 VGPRs)
typedef __attribute__((ext_vector_type(4))) float f32x4;

// RNE float -> bf16 bits (no NaN inputs here)
static __device__ __forceinline__ unsigned short f2bf(float f) {
    unsigned int u = __float_as_uint(f);
    u += 0x7fffu + ((u >> 16) & 1u);
    return (unsigned short)(u >> 16);
}

// ---------------------------------------------------------------------------
// Prep: Wt[m][d][e] = bf16(W_m[e][d]),  m in {q,k,v}.  3*64*1024 elements.
// Wq is pre-scaled by log2(e)/sqrt(64) so attn needs no scale multiply.
// ---------------------------------------------------------------------------
__global__ __launch_bounds__(256) void wprep_kernel(
        const float* __restrict__ Wq, const float* __restrict__ Wk,
        const float* __restrict__ Wv, unsigned short* __restrict__ Wt) {
    int idx = blockIdx.x * 256 + threadIdx.x;       // < 3*65536
    int m = idx >> 16;
    int r = idx & 65535;
    int d = r >> 10;
    int e = r & 1023;
    const float* W = (m == 0) ? Wq : (m == 1) ? Wk : Wv;
    float v = W[e * HD + d];
    if (m == 0) v *= 0.18033688011111793f;          // log2(e)/sqrt(64)
    Wt[idx] = f2bf(v);
}

// ---------------------------------------------------------------------------
// QKV projection: 32-row blocks, fused m, 4-wave K-split (256 K each, 8 steps).
// Per kk-step: 4 H-loads (2 rowtiles) feed 12 B-frags shared by 24 MFMAs.
// H loads ping-pong prefetched one step ahead (HBM latency hidden).
// Reduce: pairwise via LDS; final tile staged in LDS; parallel epilogue:
// all 256 threads store Q/K as short8 (16B) and V as packed u32 pairs.
// V layout: Vt[b][d][s'] with per-32-block key permutation
//   sigma(t) = ((t&12)<<1) | (t&3) | ((t&16)>>2)
// (matches attn's in-register P fragment; consecutive even t -> consecutive p).
// ---------------------------------------------------------------------------
__global__ __launch_bounds__(256, 2) void qkv_kernel(
        const float* __restrict__ H, const unsigned short* __restrict__ Wt,
        unsigned short* __restrict__ Qb, unsigned short* __restrict__ Kb,
        unsigned short* __restrict__ Vt) {
    __shared__ float lds_red[2][32][192];   // 48 KB
    const int tid  = threadIdx.x;
    const int wid  = tid >> 6;
    const int lane = tid & 63;
    const int lr = lane & 15, lg = lane >> 4;
    const int rowbase = blockIdx.x * 32;

    const float* __restrict__ a0p = H + (size_t)(rowbase + lr) * EMB + wid * 256 + lg * 8;
    const float* __restrict__ a1p = a0p + 16 * EMB;
    const unsigned short* __restrict__ wb = Wt + wid * 256 + lg * 8;

    f32x4 acc[2][3][4];
    #pragma unroll
    for (int rt = 0; rt < 2; ++rt)
        #pragma unroll
        for (int m = 0; m < 3; ++m)
            #pragma unroll
            for (int nt = 0; nt < 4; ++nt)
                acc[rt][m][nt] = f32x4{0.f, 0.f, 0.f, 0.f};

    f32x4 hA0, hA1, hA2, hA3, hB0, hB1, hB2, hB3;

    auto compute_step = [&](f32x4& h0, f32x4& h1, f32x4& h2, f32x4& h3, int kk) {
        short8 af0, af1;
        #pragma unroll
        for (int j = 0; j < 4; ++j) {
            af0[j]     = (short)f2bf(h0[j]);
            af0[4 + j] = (short)f2bf(h1[j]);
            af1[j]     = (short)f2bf(h2[j]);
            af1[4 + j] = (short)f2bf(h3[j]);
        }
        #pragma unroll
        for (int m = 0; m < 3; ++m) {
            #pragma unroll
            for (int nt = 0; nt < 4; ++nt) {
                short8 bf_ = *(const short8*)(wb + m * 65536 + (nt * 16 + lr) * EMB + kk);
                acc[0][m][nt] = __builtin_amdgcn_mfma_f32_16x16x32_bf16(af0, bf_, acc[0][m][nt], 0, 0, 0);
                acc[1][m][nt] = __builtin_amdgcn_mfma_f32_16x16x32_bf16(af1, bf_, acc[1][m][nt], 0, 0, 0);
            }
        }
    };

    // prologue: load kk=0
    hA0 = *(const f32x4*)(a0p);  hA1 = *(const f32x4*)(a0p + 4);
    hA2 = *(const f32x4*)(a1p);  hA3 = *(const f32x4*)(a1p + 4);

    #pragma unroll
    for (int kko = 0; kko < 4; ++kko) {
        const int kk = kko * 64;
        hB0 = *(const f32x4*)(a0p + kk + 32);  hB1 = *(const f32x4*)(a0p + kk + 36);
        hB2 = *(const f32x4*)(a1p + kk + 32);  hB3 = *(const f32x4*)(a1p + kk + 36);
        compute_step(hA0, hA1, hA2, hA3, kk);
        if (kko < 3) {
            hA0 = *(const f32x4*)(a0p + kk + 64);  hA1 = *(const f32x4*)(a0p + kk + 68);
            hA2 = *(const f32x4*)(a1p + kk + 64);  hA3 = *(const f32x4*)(a1p + kk + 68);
        }
        compute_step(hB0, hB1, hB2, hB3, kk + 32);
    }

    // ---- pairwise cross-wave reduction
    if (wid >= 2) {
        #pragma unroll
        for (int rt = 0; rt < 2; ++rt)
            #pragma unroll
            for (int m = 0; m < 3; ++m)
                #pragma unroll
                for (int nt = 0; nt < 4; ++nt)
                    #pragma unroll
                    for (int r = 0; r < 4; ++r)
                        lds_red[wid - 2][rt * 16 + lg * 4 + r][m * 64 + nt * 16 + lr] = acc[rt][m][nt][r];
    }
    __syncthreads();
    if (wid < 2) {
        #pragma unroll
        for (int rt = 0; rt < 2; ++rt)
            #pragma unroll
            for (int m = 0; m < 3; ++m)
                #pragma unroll
                for (int nt = 0; nt < 4; ++nt)
                    #pragma unroll
                    for (int r = 0; r < 4; ++r)
                        acc[rt][m][nt][r] += lds_red[wid][rt * 16 + lg * 4 + r][m * 64 + nt * 16 + lr];
    }
    __syncthreads();
    if (wid == 1) {
        #pragma unroll
        for (int rt = 0; rt < 2; ++rt)
            #pragma unroll
            for (int m = 0; m < 3; ++m)
                #pragma unroll
                for (int nt = 0; nt < 4; ++nt)
                    #pragma unroll
                    for (int r = 0; r < 4; ++r)
                        lds_red[0][rt * 16 + lg * 4 + r][m * 64 + nt * 16 + lr] = acc[rt][m][nt][r];
    }
    __syncthreads();
    if (wid == 0) {
        #pragma unroll
        for (int rt = 0; rt < 2; ++rt)
            #pragma unroll
            for (int m = 0; m < 3; ++m)
                #pragma unroll
                for (int nt = 0; nt < 4; ++nt)
                    #pragma unroll
                    for (int r = 0; r < 4; ++r) {
                        int row = rt * 16 + lg * 4 + r;
                        int col = m * 64 + nt * 16 + lr;
                        lds_red[0][row][col] += acc[rt][m][nt][r];
                    }
    }
    __syncthreads();

    // ---- parallel epilogue: 256 threads store from lds_red[0]
    {
        const int row = tid >> 3;            // 0..31
        const int d0  = (tid & 7) * 8;       // 0,8,...,56
        const size_t grow = (size_t)(rowbase + row);
        short8 uq, uk;
        #pragma unroll
        for (int j = 0; j < 8; ++j) {
            uq[j] = (short)f2bf(lds_red[0][row][d0 + j]);
            uk[j] = (short)f2bf(lds_red[0][row][64 + d0 + j]);
        }
        *(short8*)(Qb + grow * HD + d0) = uq;
        *(short8*)(Kb + grow * HD + d0) = uk;
    }
    {
        const int d  = tid >> 2;             // 0..63
        const int j  = tid & 3;
        const int b  = rowbase >> 12;
        const int sl = rowbase & (SEQ - 1);
        unsigned short* vrow = Vt + ((size_t)b * HD + d) * SEQ + sl;
        #pragma unroll
        for (int k4 = 0; k4 < 4; ++k4) {
            int t0 = j * 2 + k4 * 8;         // even t in 0..30
            int p0 = ((t0 & 12) << 1) | (t0 & 3) | ((t0 & 16) >> 2);
            unsigned int val = (unsigned int)f2bf(lds_red[0][t0][128 + d])
                             | ((unsigned int)f2bf(lds_red[0][t0 + 1][128 + d]) << 16);
            *(unsigned int*)(vrow + p0) = val;
        }
    }
}

// ---------------------------------------------------------------------------
// Flash attention, causal, split-K within a block, SWAPPED QK^T, 2-stage
// software pipeline: K and V for iteration it+8 load into named registers
// while iteration it computes (L2 latency hidden under MFMA+softmax).
// Block = 512 thr = 8 waves over the SAME 16 q-rows; wave w handles
// iterations it = w, w+8, ... . Q is pre-scaled (wprep), softmax in exp2.
// S^T = mfma(K_frag, Q_frag): D col = q (lane&15), row = key (lg*4+r).
// P stays in registers (PV B-frag); defer-max THR=8; partials merged in LDS.
// ---------------------------------------------------------------------------
__global__ __launch_bounds__(512, 4) void attn_kernel(
        const unsigned short* __restrict__ Qb, const unsigned short* __restrict__ Kb,
        const unsigned short* __restrict__ Vt, float* __restrict__ out) {
    __shared__ float lds_o[8][16][65];     // 33.3 KB partials (padded)
    __shared__ float lds_ml[8][16][2];     // 1 KB
    const int tid  = threadIdx.x;
    const int w    = tid >> 6;
    const int lane = tid & 63;
    const int lr = lane & 15, lg = lane >> 4;

    const int bid = blockIdx.x;
    const int b   = bid & 3;
    const int i   = bid >> 2;              // 0..255
    const int p   = i & 63, h = i >> 6;
    const int qt  = (h << 6) | ((h & 1) ? (63 - p) : p);   // per-CU balance
    const int qbase = qt * 16;

    const unsigned short* __restrict__ Qp = Qb + ((size_t)b * SEQ + qbase) * HD;
    const unsigned short* __restrict__ Kp = Kb + (size_t)b * SEQ * HD;
    const unsigned short* __restrict__ Vp = Vt + (size_t)b * HD * SEQ;

    short8 qf0 = *(const short8*)(Qp + lr * HD +      lg * 8);
    short8 qf1 = *(const short8*)(Qp + lr * HD + 32 + lg * 8);

    f32x4 o[4];
    #pragma unroll
    for (int nt = 0; nt < 4; ++nt) o[nt] = f32x4{0.f, 0.f, 0.f, 0.f};
    float mrun = -1e30f;
    float lrun = 0.f;

    const int total32 = (qbase + 47) >> 5;  // # of 32-key iterations

    auto loadkv = [&](short8& k00, short8& k01, short8& k10, short8& k11,
                      short8& vf0, short8& vf1, short8& vf2, short8& vf3, int itv) {
        const unsigned short* kp_ = Kp + (size_t)(itv * 32 + lr) * HD + lg * 8;
        k00 = *(const short8*)(kp_);
        k01 = *(const short8*)(kp_ + 32);
        k10 = *(const short8*)(kp_ + 16 * HD);
        k11 = *(const short8*)(kp_ + 16 * HD + 32);
        const unsigned short* vp_ = Vp + (size_t)lr * SEQ + itv * 32 + lg * 8;
        vf0 = *(const short8*)(vp_);
        vf1 = *(const short8*)(vp_ + 16 * SEQ);
        vf2 = *(const short8*)(vp_ + 32 * SEQ);
        vf3 = *(const short8*)(vp_ + 48 * SEQ);
    };

    auto compute = [&](short8& k00, short8& k01, short8& k10, short8& k11,
                       short8& vf0, short8& vf1, short8& vf2, short8& vf3, int itv) {
        const int kvb = itv * 32;
        f32x4 s0 = f32x4{0.f, 0.f, 0.f, 0.f};
        f32x4 s1 = f32x4{0.f, 0.f, 0.f, 0.f};
        s0 = __builtin_amdgcn_mfma_f32_16x16x32_bf16(k00, qf0, s0, 0, 0, 0);
        s0 = __builtin_amdgcn_mfma_f32_16x16x32_bf16(k01, qf1, s0, 0, 0, 0);
        s1 = __builtin_amdgcn_mfma_f32_16x16x32_bf16(k10, qf0, s1, 0, 0, 0);
        s1 = __builtin_amdgcn_mfma_f32_16x16x32_bf16(k11, qf1, s1, 0, 0, 0);

        float v0[4], v1[4];
        #pragma unroll
        for (int r = 0; r < 4; ++r) { v0[r] = s0[r]; v1[r] = s1[r]; }
        if (kvb + 31 > qbase) {            // diagonal tile: causal mask
            const int qg = qbase + lr;
            #pragma unroll
            for (int r = 0; r < 4; ++r) {
                if (kvb + lg * 4 + r      > qg) v0[r] = -1e30f;
                if (kvb + 16 + lg * 4 + r > qg) v1[r] = -1e30f;
            }
        }

        float mx = fmaxf(fmaxf(fmaxf(v0[0], v0[1]), fmaxf(v0[2], v0[3])),
                         fmaxf(fmaxf(v1[0], v1[1]), fmaxf(v1[2], v1[3])));
        mx = fmaxf(mx, __shfl_xor(mx, 16));
        mx = fmaxf(mx, __shfl_xor(mx, 32));

        if (!__all(mx <= mrun + 8.f)) {
            float mnew = fmaxf(mrun, mx);
            float f = exp2f(mrun - mnew);
            mrun = mnew;
            lrun *= f;
            #pragma unroll
            for (int nt = 0; nt < 4; ++nt) o[nt] *= f;
        }

        short8 pb;
        float rs = 0.f;
        #pragma unroll
        for (int r = 0; r < 4; ++r) {
            float p0 = exp2f(v0[r] - mrun);
            float p1 = exp2f(v1[r] - mrun);
            rs += p0 + p1;
            pb[r]     = (short)f2bf(p0);
            pb[4 + r] = (short)f2bf(p1);
        }
        lrun += rs;

        o[0] = __builtin_amdgcn_mfma_f32_16x16x32_bf16(vf0, pb, o[0], 0, 0, 0);
        o[1] = __builtin_amdgcn_mfma_f32_16x16x32_bf16(vf1, pb, o[1], 0, 0, 0);
        o[2] = __builtin_amdgcn_mfma_f32_16x16x32_bf16(vf2, pb, o[2], 0, 0, 0);
        o[3] = __builtin_amdgcn_mfma_f32_16x16x32_bf16(vf3, pb, o[3], 0, 0, 0);
    };

    int it = w;
    if (it < total32) {
        short8 k00A, k01A, k10A, k11A, vf0A, vf1A, vf2A, vf3A;
        short8 k00B, k01B, k10B, k11B, vf0B, vf1B, vf2B, vf3B;
        loadkv(k00A, k01A, k10A, k11A, vf0A, vf1A, vf2A, vf3A, it);
        while (true) {
            int itn = it + 8;
            bool moreB = itn < total32;
            if (moreB) loadkv(k00B, k01B, k10B, k11B, vf0B, vf1B, vf2B, vf3B, itn);
            compute(k00A, k01A, k10A, k11A, vf0A, vf1A, vf2A, vf3A, it);
            if (!moreB) break;
            it = itn; itn += 8;
            bool moreA = itn < total32;
            if (moreA) loadkv(k00A, k01A, k10A, k11A, vf0A, vf1A, vf2A, vf3A, itn);
            compute(k00B, k01B, k10B, k11B, vf0B, vf1B, vf2B, vf3B, it);
            if (!moreA) break;
            it = itn;
        }
    }

    // per-lane lrun -> per-q total (sum across lg groups)
    lrun += __shfl_xor(lrun, 16);
    lrun += __shfl_xor(lrun, 32);

    // ---- write partials: o[nt][r] = O[q=lr][d = nt*16+lg*4+r]
    #pragma unroll
    for (int nt = 0; nt < 4; ++nt)
        #pragma unroll
        for (int r = 0; r < 4; ++r)
            lds_o[w][lr][nt * 16 + lg * 4 + r] = o[nt][r];
    if (lane < 16) {
        lds_ml[w][lane][0] = mrun;
        lds_ml[w][lane][1] = lrun;
    }
    __syncthreads();

    // ---- merge 8 partials: 512 threads over 16 rows x 32 col-pairs
    const int row = tid >> 5;
    const int c2  = (tid & 31) * 2;
    float M = -1e30f;
    #pragma unroll
    for (int ww = 0; ww < 8; ++ww) M = fmaxf(M, lds_ml[ww][row][0]);
    float L = 0.f, a0 = 0.f, a1 = 0.f;
    #pragma unroll
    for (int ww = 0; ww < 8; ++ww) {
        float wt = exp2f(lds_ml[ww][row][0] - M);
        L  += wt * lds_ml[ww][row][1];
        a0 += wt * lds_o[ww][row][c2];
        a1 += wt * lds_o[ww][row][c2 + 1];
    }
    float invL = 1.0f / L;
    float2 res;
    res.x = a0 * invL;
    res.y = a1 * invL;
    *(float2*)(out + ((size_t)b * SEQ + qbase + row) * HD + c2) = res;
}

// ---------------------------------------------------------------------------
extern "C" void kernel_launch(void* const* d_in, const int* in_sizes, int n_in,
                              void* d_out, int out_size, void* d_ws, size_t ws_size,
                              hipStream_t stream) {
    const float* H  = (const float*)d_in[0];
    const float* Wq = (const float*)d_in[1];
    const float* Wk = (const float*)d_in[2];
    const float* Wv = (const float*)d_in[3];
    float* out = (float*)d_out;

    // workspace layout (bf16): Qb[16384*64] | Kb[16384*64] | Vt[4][64][4096] | Wt[3][64][1024]
    unsigned short* Qb = (unsigned short*)d_ws;
    unsigned short* Kb = Qb + (size_t)NB * SEQ * HD;
    unsigned short* Vt = Kb + (size_t)NB * SEQ * HD;
    unsigned short* Wt = Vt + (size_t)NB * SEQ * HD;
    // total = (3*4*4096*64 + 3*64*1024) * 2 bytes ~= 6.4 MB

    wprep_kernel<<<768, 256, 0, stream>>>(Wq, Wk, Wv, Wt);
    qkv_kernel<<<NB * SEQ / 32, 256, 0, stream>>>(H, Wt, Qb, Kb, Vt);
    attn_kernel<<<NB * (SEQ / 16), 512, 0, stream>>>(Qb, Kb, Vt, out);
}

// Round 8
// 110.447 us; speedup vs baseline: 2.3075x; 1.0200x over previous
//
#include <hip/hip_runtime.h>
#include <hip/hip_bf16.h>
#include <stdint.h>

#define SEQ 4096
#define EMB 1024
#define HD  64
#define NB  4

typedef __attribute__((ext_vector_type(8))) short short8;   // 8 x bf16 (4 VGPRs)
typedef __attribute__((ext_vector_type(4))) float f32x4;

// RNE float -> bf16 bits (no NaN inputs here)
static __device__ __forceinline__ unsigned short f2bf(float f) {
    unsigned int u = __float_as_uint(f);
    u += 0x7fffu + ((u >> 16) & 1u);
    return (unsigned short)(u >> 16);
}

// ---------------------------------------------------------------------------
// Prep: Wt[m][d][e] = bf16(W_m[e][d]),  m in {q,k,v}.  3*64*1024 elements.
// Wq is pre-scaled by log2(e)/sqrt(64) so attn needs no scale multiply.
// ---------------------------------------------------------------------------
__global__ __launch_bounds__(256) void wprep_kernel(
        const float* __restrict__ Wq, const float* __restrict__ Wk,
        const float* __restrict__ Wv, unsigned short* __restrict__ Wt) {
    int idx = blockIdx.x * 256 + threadIdx.x;       // < 3*65536
    int m = idx >> 16;
    int r = idx & 65535;
    int d = r >> 10;
    int e = r & 1023;
    const float* W = (m == 0) ? Wq : (m == 1) ? Wk : Wv;
    float v = W[e * HD + d];
    if (m == 0) v *= 0.18033688011111793f;          // log2(e)/sqrt(64)
    Wt[idx] = f2bf(v);
}

// ---------------------------------------------------------------------------
// QKV projection: 32-row blocks, fused m, 4-wave K-split (256 K each, 8 steps).
// Per kk-step: 4 H-loads (2 rowtiles) feed 12 B-frags shared by 24 MFMAs.
// H loads ping-pong prefetched one step ahead (HBM latency hidden).
// Reduce: pairwise via LDS; final tile staged in LDS; parallel epilogue:
// all 256 threads store Q/K as short8 (16B) and V as packed u32 pairs.
// V layout: Vt[b][d][s'] with per-32-block key permutation
//   sigma(t) = ((t&12)<<1) | (t&3) | ((t&16)>>2)
// (matches attn's in-register P fragment; consecutive even t -> consecutive p).
// ---------------------------------------------------------------------------
__global__ __launch_bounds__(256, 2) void qkv_kernel(
        const float* __restrict__ H, const unsigned short* __restrict__ Wt,
        unsigned short* __restrict__ Qb, unsigned short* __restrict__ Kb,
        unsigned short* __restrict__ Vt) {
    __shared__ float lds_red[2][32][192];   // 48 KB
    const int tid  = threadIdx.x;
    const int wid  = tid >> 6;
    const int lane = tid & 63;
    const int lr = lane & 15, lg = lane >> 4;
    const int rowbase = blockIdx.x * 32;

    const float* __restrict__ a0p = H + (size_t)(rowbase + lr) * EMB + wid * 256 + lg * 8;
    const float* __restrict__ a1p = a0p + 16 * EMB;
    const unsigned short* __restrict__ wb = Wt + wid * 256 + lg * 8;

    f32x4 acc[2][3][4];
    #pragma unroll
    for (int rt = 0; rt < 2; ++rt)
        #pragma unroll
        for (int m = 0; m < 3; ++m)
            #pragma unroll
            for (int nt = 0; nt < 4; ++nt)
                acc[rt][m][nt] = f32x4{0.f, 0.f, 0.f, 0.f};

    f32x4 hA0, hA1, hA2, hA3, hB0, hB1, hB2, hB3;

    auto compute_step = [&](f32x4& h0, f32x4& h1, f32x4& h2, f32x4& h3, int kk) {
        short8 af0, af1;
        #pragma unroll
        for (int j = 0; j < 4; ++j) {
            af0[j]     = (short)f2bf(h0[j]);
            af0[4 + j] = (short)f2bf(h1[j]);
            af1[j]     = (short)f2bf(h2[j]);
            af1[4 + j] = (short)f2bf(h3[j]);
        }
        #pragma unroll
        for (int m = 0; m < 3; ++m) {
            #pragma unroll
            for (int nt = 0; nt < 4; ++nt) {
                short8 bf_ = *(const short8*)(wb + m * 65536 + (nt * 16 + lr) * EMB + kk);
                acc[0][m][nt] = __builtin_amdgcn_mfma_f32_16x16x32_bf16(af0, bf_, acc[0][m][nt], 0, 0, 0);
                acc[1][m][nt] = __builtin_amdgcn_mfma_f32_16x16x32_bf16(af1, bf_, acc[1][m][nt], 0, 0, 0);
            }
        }
    };

    // prologue: load kk=0
    hA0 = *(const f32x4*)(a0p);  hA1 = *(const f32x4*)(a0p + 4);
    hA2 = *(const f32x4*)(a1p);  hA3 = *(const f32x4*)(a1p + 4);

    #pragma unroll
    for (int kko = 0; kko < 4; ++kko) {
        const int kk = kko * 64;
        hB0 = *(const f32x4*)(a0p + kk + 32);  hB1 = *(const f32x4*)(a0p + kk + 36);
        hB2 = *(const f32x4*)(a1p + kk + 32);  hB3 = *(const f32x4*)(a1p + kk + 36);
        compute_step(hA0, hA1, hA2, hA3, kk);
        if (kko < 3) {
            hA0 = *(const f32x4*)(a0p + kk + 64);  hA1 = *(const f32x4*)(a0p + kk + 68);
            hA2 = *(const f32x4*)(a1p + kk + 64);  hA3 = *(const f32x4*)(a1p + kk + 68);
        }
        compute_step(hB0, hB1, hB2, hB3, kk + 32);
    }

    // ---- pairwise cross-wave reduction
    if (wid >= 2) {
        #pragma unroll
        for (int rt = 0; rt < 2; ++rt)
            #pragma unroll
            for (int m = 0; m < 3; ++m)
                #pragma unroll
                for (int nt = 0; nt < 4; ++nt)
                    #pragma unroll
                    for (int r = 0; r < 4; ++r)
                        lds_red[wid - 2][rt * 16 + lg * 4 + r][m * 64 + nt * 16 + lr] = acc[rt][m][nt][r];
    }
    __syncthreads();
    if (wid < 2) {
        #pragma unroll
        for (int rt = 0; rt < 2; ++rt)
            #pragma unroll
            for (int m = 0; m < 3; ++m)
                #pragma unroll
                for (int nt = 0; nt < 4; ++nt)
                    #pragma unroll
                    for (int r = 0; r < 4; ++r)
                        acc[rt][m][nt][r] += lds_red[wid][rt * 16 + lg * 4 + r][m * 64 + nt * 16 + lr];
    }
    __syncthreads();
    if (wid == 1) {
        #pragma unroll
        for (int rt = 0; rt < 2; ++rt)
            #pragma unroll
            for (int m = 0; m < 3; ++m)
                #pragma unroll
                for (int nt = 0; nt < 4; ++nt)
                    #pragma unroll
                    for (int r = 0; r < 4; ++r)
                        lds_red[0][rt * 16 + lg * 4 + r][m * 64 + nt * 16 + lr] = acc[rt][m][nt][r];
    }
    __syncthreads();
    if (wid == 0) {
        #pragma unroll
        for (int rt = 0; rt < 2; ++rt)
            #pragma unroll
            for (int m = 0; m < 3; ++m)
                #pragma unroll
                for (int nt = 0; nt < 4; ++nt)
                    #pragma unroll
                    for (int r = 0; r < 4; ++r) {
                        int row = rt * 16 + lg * 4 + r;
                        int col = m * 64 + nt * 16 + lr;
                        lds_red[0][row][col] += acc[rt][m][nt][r];
                    }
    }
    __syncthreads();

    // ---- parallel epilogue: 256 threads store from lds_red[0]
    {
        const int row = tid >> 3;            // 0..31
        const int d0  = (tid & 7) * 8;       // 0,8,...,56
        const size_t grow = (size_t)(rowbase + row);
        short8 uq, uk;
        #pragma unroll
        for (int j = 0; j < 8; ++j) {
            uq[j] = (short)f2bf(lds_red[0][row][d0 + j]);
            uk[j] = (short)f2bf(lds_red[0][row][64 + d0 + j]);
        }
        *(short8*)(Qb + grow * HD + d0) = uq;
        *(short8*)(Kb + grow * HD + d0) = uk;
    }
    {
        const int d  = tid >> 2;             // 0..63
        const int j  = tid & 3;
        const int b  = rowbase >> 12;
        const int sl = rowbase & (SEQ - 1);
        unsigned short* vrow = Vt + ((size_t)b * HD + d) * SEQ + sl;
        #pragma unroll
        for (int k4 = 0; k4 < 4; ++k4) {
            int t0 = j * 2 + k4 * 8;         // even t in 0..30
            int p0 = ((t0 & 12) << 1) | (t0 & 3) | ((t0 & 16) >> 2);
            unsigned int val = (unsigned int)f2bf(lds_red[0][t0][128 + d])
                             | ((unsigned int)f2bf(lds_red[0][t0 + 1][128 + d]) << 16);
            *(unsigned int*)(vrow + p0) = val;
        }
    }
}

// ---------------------------------------------------------------------------
// Flash attention, causal, split-K within a block, SWAPPED QK^T.
// XCD-AFFINE MAPPING: xcd = bid&7 owns batch b = xcd&3 exclusively, so each
// XCD's L2 working set is ONE batch's K+V+Q (~2.5 MB < 4 MB L2) instead of
// all four (~6 MB -> L3 thrash). slot zigzag keeps per-CU qt-sums constant.
// Block = 512 thr = 8 waves over the SAME 16 q-rows; wave w handles
// iterations it = w, w+8, ... . Q pre-scaled (wprep), softmax in exp2.
// S^T = mfma(K_frag, Q_frag): D col = q (lane&15), row = key (lg*4+r).
// P stays in registers (PV B-frag); defer-max THR=8; partials merged in LDS.
// ---------------------------------------------------------------------------
__global__ __launch_bounds__(512, 8) void attn_kernel(
        const unsigned short* __restrict__ Qb, const unsigned short* __restrict__ Kb,
        const unsigned short* __restrict__ Vt, float* __restrict__ out) {
    __shared__ float lds_o[8][16][65];     // 33.3 KB partials (padded)
    __shared__ float lds_ml[8][16][2];     // 1 KB
    const int tid  = threadIdx.x;
    const int w    = tid >> 6;
    const int lane = tid & 63;
    const int lr = lane & 15, lg = lane >> 4;

    const int bid  = blockIdx.x;
    const int xcd  = bid & 7;              // dispatch round-robins XCDs
    const int slot = bid >> 3;             // 0..127 within this XCD
    const int b    = xcd & 3;              // batch pinned to XCD
    const int pz   = slot & 31, hh = slot >> 5;
    const int qtl  = (hh << 5) | ((hh & 1) ? (31 - pz) : pz);  // per-CU balance
    const int qt   = (qtl << 1) | (xcd >> 2);
    const int qbase = qt * 16;

    const unsigned short* __restrict__ Qp = Qb + ((size_t)b * SEQ + qbase) * HD;
    const unsigned short* __restrict__ Kp = Kb + (size_t)b * SEQ * HD;
    const unsigned short* __restrict__ Vp = Vt + (size_t)b * HD * SEQ;

    short8 qf0 = *(const short8*)(Qp + lr * HD +      lg * 8);
    short8 qf1 = *(const short8*)(Qp + lr * HD + 32 + lg * 8);

    f32x4 o[4];
    #pragma unroll
    for (int nt = 0; nt < 4; ++nt) o[nt] = f32x4{0.f, 0.f, 0.f, 0.f};
    float mrun = -1e30f;
    float lrun = 0.f;

    const int total32 = (qbase + 47) >> 5;  // # of 32-key iterations

    for (int it = w; it < total32; it += 8) {
        const int kvb = it * 32;
        const unsigned short* kp0 = Kp + (size_t)(kvb + lr) * HD + lg * 8;
        const unsigned short* kp1 = kp0 + 16 * HD;

        f32x4 s0 = f32x4{0.f, 0.f, 0.f, 0.f};
        f32x4 s1 = f32x4{0.f, 0.f, 0.f, 0.f};
        {
            short8 k00 = *(const short8*)(kp0);
            short8 k01 = *(const short8*)(kp0 + 32);
            short8 k10 = *(const short8*)(kp1);
            short8 k11 = *(const short8*)(kp1 + 32);
            // swapped: A = K rows (keys), B = Q rows (q) -> S^T
            s0 = __builtin_amdgcn_mfma_f32_16x16x32_bf16(k00, qf0, s0, 0, 0, 0);
            s0 = __builtin_amdgcn_mfma_f32_16x16x32_bf16(k01, qf1, s0, 0, 0, 0);
            s1 = __builtin_amdgcn_mfma_f32_16x16x32_bf16(k10, qf0, s1, 0, 0, 0);
            s1 = __builtin_amdgcn_mfma_f32_16x16x32_bf16(k11, qf1, s1, 0, 0, 0);
        }

        float v0[4], v1[4];
        #pragma unroll
        for (int r = 0; r < 4; ++r) { v0[r] = s0[r]; v1[r] = s1[r]; }
        if (kvb + 31 > qbase) {            // diagonal tile: causal mask
            const int qg = qbase + lr;
            #pragma unroll
            for (int r = 0; r < 4; ++r) {
                if (kvb + lg * 4 + r      > qg) v0[r] = -1e30f;
                if (kvb + 16 + lg * 4 + r > qg) v1[r] = -1e30f;
            }
        }

        // per-lane max over this lane's 8 keys, then cross-lg (same q) reduce
        float mx = fmaxf(fmaxf(fmaxf(v0[0], v0[1]), fmaxf(v0[2], v0[3])),
                         fmaxf(fmaxf(v1[0], v1[1]), fmaxf(v1[2], v1[3])));
        mx = fmaxf(mx, __shfl_xor(mx, 16));
        mx = fmaxf(mx, __shfl_xor(mx, 32));

        // defer-max: only rescale when max grew by more than THR=8
        if (!__all(mx <= mrun + 8.f)) {
            float mnew = fmaxf(mrun, mx);
            float f = exp2f(mrun - mnew);
            mrun = mnew;
            lrun *= f;
            #pragma unroll
            for (int nt = 0; nt < 4; ++nt) o[nt] *= f;
        }

        short8 pb;
        float rs = 0.f;
        #pragma unroll
        for (int r = 0; r < 4; ++r) {
            float p0 = exp2f(v0[r] - mrun);
            float p1 = exp2f(v1[r] - mrun);
            rs += p0 + p1;
            pb[r]     = (short)f2bf(p0);
            pb[4 + r] = (short)f2bf(p1);
        }
        lrun += rs;

        #pragma unroll
        for (int nt = 0; nt < 4; ++nt) {
            short8 vf = *(const short8*)(Vp + (size_t)(nt * 16 + lr) * SEQ + kvb + lg * 8);
            o[nt] = __builtin_amdgcn_mfma_f32_16x16x32_bf16(vf, pb, o[nt], 0, 0, 0);
        }
    }

    // per-lane lrun -> per-q total (sum across lg groups)
    lrun += __shfl_xor(lrun, 16);
    lrun += __shfl_xor(lrun, 32);

    // ---- write partials: o[nt][r] = O[q=lr][d = nt*16+lg*4+r]
    #pragma unroll
    for (int nt = 0; nt < 4; ++nt)
        #pragma unroll
        for (int r = 0; r < 4; ++r)
            lds_o[w][lr][nt * 16 + lg * 4 + r] = o[nt][r];
    if (lane < 16) {
        lds_ml[w][lane][0] = mrun;
        lds_ml[w][lane][1] = lrun;
    }
    __syncthreads();

    // ---- merge 8 partials: 512 threads over 16 rows x 32 col-pairs
    const int row = tid >> 5;
    const int c2  = (tid & 31) * 2;
    float M = -1e30f;
    #pragma unroll
    for (int ww = 0; ww < 8; ++ww) M = fmaxf(M, lds_ml[ww][row][0]);
    float L = 0.f, a0 = 0.f, a1 = 0.f;
    #pragma unroll
    for (int ww = 0; ww < 8; ++ww) {
        float wt = exp2f(lds_ml[ww][row][0] - M);
        L  += wt * lds_ml[ww][row][1];
        a0 += wt * lds_o[ww][row][c2];
        a1 += wt * lds_o[ww][row][c2 + 1];
    }
    float invL = 1.0f / L;
    float2 res;
    res.x = a0 * invL;
    res.y = a1 * invL;
    *(float2*)(out + ((size_t)b * SEQ + qbase + row) * HD + c2) = res;
}

// ---------------------------------------------------------------------------
extern "C" void kernel_launch(void* const* d_in, const int* in_sizes, int n_in,
                              void* d_out, int out_size, void* d_ws, size_t ws_size,
                              hipStream_t stream) {
    const float* H  = (const float*)d_in[0];
    const float* Wq = (const float*)d_in[1];
    const float* Wk = (const float*)d_in[2];
    const float* Wv = (const float*)d_in[3];
    float* out = (float*)d_out;

    // workspace layout (bf16): Qb[16384*64] | Kb[16384*64] | Vt[4][64][4096] | Wt[3][64][1024]
    unsigned short* Qb = (unsigned short*)d_ws;
    unsigned short* Kb = Qb + (size_t)NB * SEQ * HD;
    unsigned short* Vt = Kb + (size_t)NB * SEQ * HD;
    unsigned short* Wt = Vt + (size_t)NB * SEQ * HD;
    // total = (3*4*4096*64 + 3*64*1024) * 2 bytes ~= 6.4 MB

    wprep_kernel<<<768, 256, 0, stream>>>(Wq, Wk, Wv, Wt);
    qkv_kernel<<<NB * SEQ / 32, 256, 0, stream>>>(H, Wt, Qb, Kb, Vt);
    attn_kernel<<<NB * (SEQ / 16), 512, 0, stream>>>(Qb, Kb, Vt, out);
}